// Round 8
// baseline (190.023 us; speedup 1.0000x reference)
//
#include <hip/hip_runtime.h>
#include <hip/hip_bf16.h>
#include <stdint.h>

#define NROWS 8192
#define NDIM  512
#define MARGIN 0.3f
#define NT    2080     // 64*65/2 upper-triangular 128x128 blocks

typedef __attribute__((ext_vector_type(4))) float floatx4;

// pack 4 floats -> 4 OCP e4m3 bytes (HW cvt, RNE, saturating)
__device__ inline unsigned cvt4_fp8(float4 f) {
  int v = 0;
  v = __builtin_amdgcn_cvt_pk_fp8_f32(f.x, f.y, v, false);  // low 2 bytes
  v = __builtin_amdgcn_cvt_pk_fp8_f32(f.z, f.w, v, true);   // high 2 bytes
  return (unsigned)v;
}

// fp32 -> fp8 e4m3, 16 floats/thread (64B read, 16B write); zeroes output
__global__ void convert_kernel(const float4* __restrict__ in, uint4* __restrict__ out,
                               float* __restrict__ loss_out) {
  int i = blockIdx.x * blockDim.x + threadIdx.x;
  if (i == 0) loss_out[0] = 0.f;          // d_out poisoned each replay
  float4 f0 = in[i * 4 + 0], f1 = in[i * 4 + 1], f2 = in[i * 4 + 2], f3 = in[i * 4 + 3];
  uint4 o;
  o.x = cvt4_fp8(f0);
  o.y = cvt4_fp8(f1);
  o.z = cvt4_fp8(f2);
  o.w = cvt4_fp8(f3);
  out[i] = o;
}

__device__ inline void gload_lds16(const void* g, void* l) {
  __builtin_amdgcn_global_load_lds(
      (const __attribute__((address_space(1))) unsigned int*)g,
      (__attribute__((address_space(3))) unsigned int*)l, 16, 0, 0);
}

// 128x128 upper-tri blocks of sim = X·X^T in fp8 e4m3 (non-scaled MFMA = bf16
// rate, half the staging/LDS bytes of bf16). R7 skeleton: 4 waves (2x2 of
// 64x64), BK=32, 3-stage LDS pipeline (24 KB -> 6 blocks/CU), raw s_barrier
// with per-wave fine-grained vmcnt (never 0 mid-loop), distance-2 prefetch.
// Per stage each wave issues just 2 DMA loads (1 KB chunk of A + of B).
__launch_bounds__(256, 6)
__global__ void loss_kernel(const unsigned char* __restrict__ Xb, const int* __restrict__ tg,
                            float* __restrict__ out) {
  __shared__ __align__(16) unsigned char As[3][4096];   // 128 rows x 32 fp8
  __shared__ __align__(16) unsigned char Bs[3][4096];
  __shared__ float red[4];

  // super-tile decode (8 diagonal supers of 36, then 28 off-diag of 64)
  int t = blockIdx.x;
  int bi, bj;
  if (t < 288) {
    int si = t / 36;
    int q  = t - si * 36;
    int ii = 0;
    while (q >= 8 - ii) { q -= 8 - ii; ii++; }
    bi = si * 8 + ii;
    bj = si * 8 + ii + q;
  } else {
    int q = t - 288;
    int s = q >> 6, r = q & 63;
    int si = 0;
    while (s >= 7 - si) { s -= 7 - si; si++; }
    int sj = si + 1 + s;
    bi = si * 8 + (r >> 3);
    bj = sj * 8 + (r & 7);
  }

  const int tid  = threadIdx.x;
  const int lane = tid & 63;
  const int w    = tid >> 6;
  const int wm   = w >> 1, wn = w & 1;   // 2x2 waves, 64x64 each
  const int quad = lane >> 4;
  const int l16  = lane & 15;

  const int rowBase = bi * 128;
  const int colBase = bj * 128;

  // ---- label preloads (issued FIRST: oldest in the per-wave vmcnt FIFO) ----
  int4 rl[4];
  int  tc[4];
#pragma unroll
  for (int mt = 0; mt < 4; mt++)
    rl[mt] = *(const int4*)(tg + rowBase + wm * 64 + mt * 16 + quad * 4);
#pragma unroll
  for (int nt = 0; nt < 4; nt++)
    tc[nt] = tg[colBase + wn * 64 + nt * 16 + l16];

  // ---- staging: tile 128x32 fp8 = 4 KB = 4 chunks of 1 KB (32 rows each);
  // wave w stages chunk w of A and chunk w of B. DMA puts lane's 16 B at
  // chunkBase + lane*16: lane = (r&31)*2 + half -> LDS addr = r*32 + half*16,
  // i.e. plain row-major. Read side: ds_read_b64 at r*32 + quad*8 (4-way bank
  // alias accepted: rows stride 8 banks; 1.58x on half-sized reads).
  const int srow = lane >> 1;            // row within 32-row chunk
  const int shlf = lane & 1;             // 16-byte half of the 32-byte row
  const unsigned gA = (unsigned)((rowBase + w * 32 + srow) * NDIM + shlf * 16);
  const unsigned gB = (unsigned)((colBase + w * 32 + srow) * NDIM + shlf * 16);

#define STAGE(KT, BUF)                                            \
  do {                                                            \
    gload_lds16(Xb + gA + (KT) * 32, &As[BUF][w * 1024]);         \
    gload_lds16(Xb + gB + (KT) * 32, &Bs[BUF][w * 1024]);         \
  } while (0)

  floatx4 acc[4][4];
#pragma unroll
  for (int a = 0; a < 4; a++)
#pragma unroll
    for (int b = 0; b < 4; b++) acc[a][b] = (floatx4)(0.f);

  STAGE(0, 0);
  STAGE(1, 1);

#pragma unroll
  for (int kt = 0; kt < 16; kt++) {
    const int buf = kt % 3;
    // own tile-kt loads landed; tile-kt+1 (2 loads) stays in flight.
    if (kt < 15) asm volatile("s_waitcnt vmcnt(2)" ::: "memory");
    else         asm volatile("s_waitcnt vmcnt(0)" ::: "memory");
    asm volatile("s_barrier" ::: "memory");      // raw barrier: NO drain
    if (kt < 14) STAGE(kt + 2, (kt + 2) % 3);    // distance-2 prefetch

    long long a[4], b[4];
#pragma unroll
    for (int mt = 0; mt < 4; mt++) {
      const int row = wm * 64 + mt * 16 + l16;
      a[mt] = *(const long long*)(&As[buf][row * 32 + quad * 8]);
    }
#pragma unroll
    for (int nt = 0; nt < 4; nt++) {
      const int row = wn * 64 + nt * 16 + l16;
      b[nt] = *(const long long*)(&Bs[buf][row * 32 + quad * 8]);
    }
#pragma unroll
    for (int mt = 0; mt < 4; mt++)
#pragma unroll
      for (int nt = 0; nt < 4; nt++)
        acc[mt][nt] = __builtin_amdgcn_mfma_f32_16x16x32_fp8_fp8(a[mt], b[nt],
                                                                 acc[mt][nt], 0, 0, 0);
  }

  // Epilogue. C/D layout: col = lane&15, row = quad*4 + reg
  float lsum = 0.f;
  const bool diag = (bi == bj);
#pragma unroll
  for (int mt = 0; mt < 4; mt++) {
    const int rloc = wm * 64 + mt * 16 + quad * 4;
    const int rlab[4] = {rl[mt].x, rl[mt].y, rl[mt].z, rl[mt].w};
#pragma unroll
    for (int nt = 0; nt < 4; nt++) {
      const int cloc = wn * 64 + nt * 16 + l16;
      const int col = colBase + cloc;
#pragma unroll
      for (int r = 0; r < 4; r++) {
        const float s = acc[mt][nt][r];
        float c = (rlab[r] == tc[nt]) ? ((s < 1.f) ? 1.f - s : 0.f)
                                      : ((s > MARGIN) ? s : 0.f);
        float wgt;
        if (!diag) {
          wgt = 2.f;
        } else {
          const int row = rowBase + rloc + r;
          wgt = (row < col) ? 2.f : ((row == col) ? 1.f : 0.f);
        }
        lsum += wgt * c;
      }
    }
  }

#pragma unroll
  for (int off = 32; off > 0; off >>= 1) lsum += __shfl_down(lsum, off, 64);
  if (lane == 0) red[w] = lsum;
  __syncthreads();
  if (tid == 0)
    atomicAdd(out, (red[0] + red[1] + red[2] + red[3]) * (1.0f / NROWS));
}

extern "C" void kernel_launch(void* const* d_in, const int* in_sizes, int n_in,
                              void* d_out, int out_size, void* d_ws, size_t ws_size,
                              hipStream_t stream) {
  const float* x = (const float*)d_in[0];
  const int* tg  = (const int*)d_in[1];
  float* out     = (float*)d_out;
  unsigned char* xb = (unsigned char*)d_ws;   // fp8 X, 4 MiB

  convert_kernel<<<(NROWS * NDIM / 16) / 256, 256, 0, stream>>>(
      (const float4*)x, (uint4*)xb, out);
  loss_kernel<<<NT, 256, 0, stream>>>(xb, tg, out);
}

// Round 9
// 110.434 us; speedup vs baseline: 1.7207x; 1.7207x over previous
//
#include <hip/hip_runtime.h>
#include <hip/hip_bf16.h>
#include <stdint.h>

#define NROWS 8192
#define NDIM  512
#define MARGIN 0.3f
#define NT    2080     // 64*65/2 upper-triangular 128x128 blocks

typedef __attribute__((ext_vector_type(4))) float floatx4;
typedef __attribute__((ext_vector_type(2))) long longx2;

// pack 4 floats -> 4 OCP e4m3 bytes (HW cvt, RNE, saturating)
__device__ inline unsigned cvt4_fp8(float4 f) {
  int v = 0;
  v = __builtin_amdgcn_cvt_pk_fp8_f32(f.x, f.y, v, false);
  v = __builtin_amdgcn_cvt_pk_fp8_f32(f.z, f.w, v, true);
  return (unsigned)v;
}

// fp32 -> fp8 e4m3, 16 floats/thread; zeroes the (poisoned) output scalar
__global__ void convert_kernel(const float4* __restrict__ in, uint4* __restrict__ out,
                               float* __restrict__ loss_out) {
  int i = blockIdx.x * blockDim.x + threadIdx.x;
  if (i == 0) loss_out[0] = 0.f;
  float4 f0 = in[i * 4 + 0], f1 = in[i * 4 + 1], f2 = in[i * 4 + 2], f3 = in[i * 4 + 3];
  uint4 o;
  o.x = cvt4_fp8(f0);
  o.y = cvt4_fp8(f1);
  o.z = cvt4_fp8(f2);
  o.w = cvt4_fp8(f3);
  out[i] = o;
}

__device__ inline void gload_lds16(const void* g, void* l) {
  __builtin_amdgcn_global_load_lds(
      (const __attribute__((address_space(1))) unsigned int*)g,
      (__attribute__((address_space(3))) unsigned int*)l, 16, 0, 0);
}

// sigma: swap bits 0 and 1 (self-inverse). LDS slot s holds global row sigma(s);
// fragment row r lives at slot sigma(r). Makes ds_read_b128 base-bank =
// 16*((l16>>1)&1) + 4*quad -> 8 lanes per 4-bank group = conflict-free, while
// the lane->k mapping stays row-independent (MFMA K-alignment preserved).
__device__ inline int sigma2(int r) {
  return (r & ~3) | ((r & 1) << 1) | ((r >> 1) & 1);
}

// 128x128 upper-tri blocks of sim = X·X^T in fp8 e4m3 (non-scaled MFMA = bf16
// rate, half the bytes everywhere). BK=64: one ds_read_b128 per fragment feeds
// TWO mfma k-steps (K-permutation legal: A,B share the lane->k map). 3-stage
// LDS pipeline (48 KB -> 3 blocks/CU), raw s_barrier + per-wave vmcnt(4).
__launch_bounds__(256, 3)
__global__ void loss_kernel(const unsigned char* __restrict__ Xb, const int* __restrict__ tg,
                            float* __restrict__ out) {
  __shared__ __align__(16) unsigned char As[3][8192];   // 128 slots x 64 B
  __shared__ __align__(16) unsigned char Bs[3][8192];
  __shared__ float red[4];

  // super-tile decode (8 diagonal supers of 36, then 28 off-diag of 64)
  int t = blockIdx.x;
  int bi, bj;
  if (t < 288) {
    int si = t / 36;
    int q  = t - si * 36;
    int ii = 0;
    while (q >= 8 - ii) { q -= 8 - ii; ii++; }
    bi = si * 8 + ii;
    bj = si * 8 + ii + q;
  } else {
    int q = t - 288;
    int s = q >> 6, r = q & 63;
    int si = 0;
    while (s >= 7 - si) { s -= 7 - si; si++; }
    int sj = si + 1 + s;
    bi = si * 8 + (r >> 3);
    bj = sj * 8 + (r & 7);
  }

  const int tid  = threadIdx.x;
  const int lane = tid & 63;
  const int w    = tid >> 6;
  const int wm   = w >> 1, wn = w & 1;   // 2x2 waves, 64x64 each
  const int quad = lane >> 4;
  const int l16  = lane & 15;

  const int rowBase = bi * 128;
  const int colBase = bj * 128;

  // ---- label preloads (pre-loop; asm memory clobbers keep them here) ----
  int4 rl[4];
  int  tc[4];
#pragma unroll
  for (int mt = 0; mt < 4; mt++)
    rl[mt] = *(const int4*)(tg + rowBase + wm * 64 + mt * 16 + quad * 4);
#pragma unroll
  for (int nt = 0; nt < 4; nt++)
    tc[nt] = tg[colBase + wn * 64 + nt * 16 + l16];

  // ---- staging: tile = 128 slots x 64 B = 8 chunks of 1 KB (16 slots each);
  // wave w stages chunks {2w, 2w+1} of A and of B (4 DMA loads/wave/iter).
  // Lane d of a chunk deposits 16 B at chunkBase + d*16 = slot (ch*16 + d>>2),
  // unit (d&3); it fetches global row sigma(slot), same k-unit (no k swizzle).
  const int slot = (lane >> 2);          // slot within 16-slot chunk
  const int unit = lane & 3;             // 16-byte unit within 64-byte row
  unsigned gA[2], gB[2];
#pragma unroll
  for (int c = 0; c < 2; c++) {
    int ch = w * 2 + c;
    int gr = sigma2(ch * 16 + slot);     // global row held by this slot
    gA[c] = (unsigned)((rowBase + gr) * NDIM + unit * 16);
    gB[c] = (unsigned)((colBase + gr) * NDIM + unit * 16);
  }

#define STAGE(KT, BUF)                                                    \
  do {                                                                    \
    _Pragma("unroll")                                                     \
    for (int c = 0; c < 2; c++) {                                         \
      int ch = w * 2 + c;                                                 \
      gload_lds16(Xb + gA[c] + (KT) * 64, &As[BUF][ch * 1024]);           \
      gload_lds16(Xb + gB[c] + (KT) * 64, &Bs[BUF][ch * 1024]);           \
    }                                                                     \
  } while (0)

  floatx4 acc[4][4];
#pragma unroll
  for (int a = 0; a < 4; a++)
#pragma unroll
    for (int b = 0; b < 4; b++) acc[a][b] = (floatx4)(0.f);

  STAGE(0, 0);
  STAGE(1, 1);

#pragma unroll
  for (int kt = 0; kt < 8; kt++) {
    const int buf = kt % 3;
    // own tile-kt loads landed; tile-kt+1 (4 loads) stays in flight.
    if (kt < 7) asm volatile("s_waitcnt vmcnt(4)" ::: "memory");
    else        asm volatile("s_waitcnt vmcnt(0)" ::: "memory");
    asm volatile("s_barrier" ::: "memory");      // raw barrier: NO drain
    if (kt < 6) STAGE(kt + 2, (kt + 2) % 3);     // distance-2 prefetch

    // one b128 per fragment = both k-steps (long0 -> step0, long1 -> step1)
    longx2 a[4], b[4];
#pragma unroll
    for (int mt = 0; mt < 4; mt++) {
      const int row = wm * 64 + mt * 16 + l16;
      a[mt] = *(const longx2*)(&As[buf][sigma2(row) * 64 + quad * 16]);
    }
#pragma unroll
    for (int nt = 0; nt < 4; nt++) {
      const int row = wn * 64 + nt * 16 + l16;
      b[nt] = *(const longx2*)(&Bs[buf][sigma2(row) * 64 + quad * 16]);
    }
#pragma unroll
    for (int mt = 0; mt < 4; mt++)
#pragma unroll
      for (int nt = 0; nt < 4; nt++) {
        acc[mt][nt] = __builtin_amdgcn_mfma_f32_16x16x32_fp8_fp8(a[mt][0], b[nt][0],
                                                                 acc[mt][nt], 0, 0, 0);
        acc[mt][nt] = __builtin_amdgcn_mfma_f32_16x16x32_fp8_fp8(a[mt][1], b[nt][1],
                                                                 acc[mt][nt], 0, 0, 0);
      }
  }

  // Epilogue. C/D layout: col = lane&15, row = quad*4 + reg
  float lsum = 0.f;
  const bool diag = (bi == bj);
#pragma unroll
  for (int mt = 0; mt < 4; mt++) {
    const int rloc = wm * 64 + mt * 16 + quad * 4;
    const int rlab[4] = {rl[mt].x, rl[mt].y, rl[mt].z, rl[mt].w};
#pragma unroll
    for (int nt = 0; nt < 4; nt++) {
      const int cloc = wn * 64 + nt * 16 + l16;
      const int col = colBase + cloc;
#pragma unroll
      for (int r = 0; r < 4; r++) {
        const float s = acc[mt][nt][r];
        float c = (rlab[r] == tc[nt]) ? ((s < 1.f) ? 1.f - s : 0.f)
                                      : ((s > MARGIN) ? s : 0.f);
        float wgt;
        if (!diag) {
          wgt = 2.f;
        } else {
          const int row = rowBase + rloc + r;
          wgt = (row < col) ? 2.f : ((row == col) ? 1.f : 0.f);
        }
        lsum += wgt * c;
      }
    }
  }

#pragma unroll
  for (int off = 32; off > 0; off >>= 1) lsum += __shfl_down(lsum, off, 64);
  if (lane == 0) red[w] = lsum;
  __syncthreads();
  if (tid == 0)
    atomicAdd(out, (red[0] + red[1] + red[2] + red[3]) * (1.0f / NROWS));
}

extern "C" void kernel_launch(void* const* d_in, const int* in_sizes, int n_in,
                              void* d_out, int out_size, void* d_ws, size_t ws_size,
                              hipStream_t stream) {
  const float* x = (const float*)d_in[0];
  const int* tg  = (const int*)d_in[1];
  float* out     = (float*)d_out;
  unsigned char* xb = (unsigned char*)d_ws;   // fp8 X, 4 MiB

  convert_kernel<<<(NROWS * NDIM / 16) / 256, 256, 0, stream>>>(
      (const float4*)x, (uint4*)xb, out);
  loss_kernel<<<NT, 256, 0, stream>>>(xb, tg, out);
}